// Round 4
// baseline (111.380 us; speedup 1.0000x reference)
//
#include <hip/hip_runtime.h>

#define DEVINL __device__ __forceinline__

namespace {

constexpr int NB   = 4;
constexpr int CINv = 512;
constexpr int HIDv = 64;
constexpr int NCl  = 11;   // NC+1 output channels
constexpr int h1v = 60, w1v = 80;
constexpr int h2v = 30, w2v = 40;
constexpr int Hf = 480, Wf = 640;
constexpr int PPB1 = h1v * w1v;     // 4800 coarse px / batch
constexpr int PPB2 = h2v * w2v;     // 1200
constexpr int NP1 = NB * PPB1;      // 19200
constexpr int NP2 = NB * PPB2;      // 4800
constexpr int PPBF = Hf * Wf;       // 307200 fine px / batch
constexpr int NPF = NB * PPBF;      // 1228800
constexpr int NSHARD = 16;          // bbx accumulator shards

// workspace layout (float elements)
constexpr size_t WS_P1  = 0;                               // 2*64*19200 partials conv1
constexpr size_t WS_P2  = WS_P1 + 2ull * HIDv * NP1;       // 2*64*4800 partials conv2
constexpr size_t WS_Z   = WS_P2 + 2ull * HIDv * NP2;       // 4*11*4800 coarse logits
constexpr size_t WS_BBX = WS_Z + (size_t)NB * NCl * PPB1;  // 16 shards x 36 x 8 ints

// output layout (float elements)
constexpr size_t OUT_SEG = (size_t)NB * NCl * PPBF;  // 13,516,800
constexpr size_t OUT_BBX = OUT_SEG + (size_t)NPF;    // +1,228,800

DEVINL int iclamp(int v, int lo, int hi) { return v < lo ? lo : (v > hi ? hi : v); }

DEVINL void async_copy16(float* lds_dst, const float* g_src) {
  __builtin_amdgcn_global_load_lds(
      (const __attribute__((address_space(1))) unsigned int*)g_src,
      (__attribute__((address_space(3))) unsigned int*)lds_dst, 16, 0, 0);
}

// ---------------------------------------------------------------------------
// Kernel 1: both 1x1 convs as K-split GEMM partials, 2-phase double-buffered.
// Tile: 64 px x 64 out, K-half = 256 (8 chunks of 32).
// A chunk (8KB) via global_load_lds dwordx4 (linear LDS layout); W chunk (8KB)
// reg-staged + late ds_write (T14).  One barrier per chunk; stage of chunk
// k+1 overlaps the 512-FMA compute of chunk k (T3-minimum, 2-phase).
// ---------------------------------------------------------------------------
template <int PPB>
DEVINL void gemm_tile(const float* __restrict__ F, const float* __restrict__ Wt,
                      float* __restrict__ P, int npix, int tile, int khalf,
                      float* Ash /*[2][2048]*/, float* Wsh /*[2][32*68]*/) {
  const int t = threadIdx.x;
  const int lane = t & 63;
  const int wv = t >> 6;
  const int pg = t & 15;       // pixel group (4 px)
  const int og = t >> 4;       // output group (4 outs)
  const int gp0 = tile * 64;
  const int c0 = khalf * 256;

  // A-staging source bases per wave-inst i: element E = wv*512+i*256+lane*4
  // cc = E>>6, px = E&63 ; 4-px groups never straddle a batch (PPB % 4 == 0).
  const float* asrc[2];
  float* adst[2][2];
#pragma unroll
  for (int i = 0; i < 2; ++i) {
    const int E = wv * 512 + i * 256 + lane * 4;
    const int cc = E >> 6, px = E & 63;
    const int gp = gp0 + px;
    const int bb = gp / PPB, pb = gp - bb * PPB;
    asrc[i] = F + ((size_t)bb * CINv + cc) * PPB + pb;   // + cb*PPB per chunk
    adst[0][i] = Ash + 0 * 2048 + wv * 512 + i * 256;
    adst[1][i] = Ash + 1 * 2048 + wv * 512 + i * 256;
  }
  // W-staging: thread covers (cc = t&31, o = e*8 + (t>>5)), e = 0..7
  const int wo = t >> 5, wc = t & 31;
  const float* wsrc = Wt + (size_t)wo * CINv + wc;       // + e*8*CINv + cb

  float acc[4][4];
#pragma unroll
  for (int i = 0; i < 4; ++i)
#pragma unroll
    for (int j = 0; j < 4; ++j) acc[i][j] = 0.f;

  // prologue: stage chunk 0 into buffer 0
  {
    float wr[8];
#pragma unroll
    for (int e = 0; e < 8; ++e) wr[e] = wsrc[(size_t)e * 8 * CINv + c0];
#pragma unroll
    for (int i = 0; i < 2; ++i)
      async_copy16(adst[0][i], asrc[i] + (size_t)c0 * PPB);
#pragma unroll
    for (int e = 0; e < 8; ++e) Wsh[wc * 68 + e * 8 + wo] = wr[e];
  }
  __syncthreads();

#pragma unroll 2
  for (int kb = 0; kb < 8; ++kb) {
    const int cur = kb & 1;
    float wr[8];
    if (kb < 7) {  // issue next-chunk staging before compute
      const int cb = c0 + (kb + 1) * 32;
#pragma unroll
      for (int e = 0; e < 8; ++e) wr[e] = wsrc[(size_t)e * 8 * CINv + cb];
#pragma unroll
      for (int i = 0; i < 2; ++i)
        async_copy16(adst[cur ^ 1][i], asrc[i] + (size_t)cb * PPB);
    }
    const float* Ab = Ash + cur * 2048;
    const float* Wb = Wsh + cur * (32 * 68);
#pragma unroll
    for (int cc = 0; cc < 32; ++cc) {
      float4 a = *reinterpret_cast<const float4*>(&Ab[cc * 64 + pg * 4]);
      float4 w = *reinterpret_cast<const float4*>(&Wb[cc * 68 + og * 4]);
      float av[4] = {a.x, a.y, a.z, a.w};
      float wvv[4] = {w.x, w.y, w.z, w.w};
#pragma unroll
      for (int i = 0; i < 4; ++i)
#pragma unroll
        for (int j = 0; j < 4; ++j)
          acc[i][j] = fmaf(av[i], wvv[j], acc[i][j]);
    }
    if (kb < 7) {
      float* Wn = Wsh + (cur ^ 1) * (32 * 68);
#pragma unroll
      for (int e = 0; e < 8; ++e) Wn[wc * 68 + e * 8 + wo] = wr[e];
    }
    __syncthreads();   // drains vm (A async) + lgkm (W writes); next buf ready
  }

  // write partials: P[(khalf*64 + o) * npix + gpix], float4 over px
#pragma unroll
  for (int j = 0; j < 4; ++j) {
    int o = og * 4 + j;
    float4 v;
    v.x = acc[0][j]; v.y = acc[1][j]; v.z = acc[2][j]; v.w = acc[3][j];
    *reinterpret_cast<float4*>(&P[((size_t)khalf * HIDv + o) * npix + gp0 + pg * 4]) = v;
  }
}

__global__ __launch_bounds__(256) void k_gemm(const float* __restrict__ f1,
                                              const float* __restrict__ f2,
                                              const float* __restrict__ w1,
                                              const float* __restrict__ w2,
                                              float* __restrict__ ws) {
  __shared__ float Ash[2 * 2048];
  __shared__ float Wsh[2 * 32 * 68];
  const int bid = blockIdx.x;
  if (bid < 600) {
    gemm_tile<PPB1>(f1, w1, ws + WS_P1, NP1, bid >> 1, bid & 1, Ash, Wsh);
  } else {
    int tt = bid - 600;
    gemm_tile<PPB2>(f2, w2, ws + WS_P2, NP2, tt >> 1, tt & 1, Ash, Wsh);
  }
}

// ---------------------------------------------------------------------------
// Kernel 2: combine partials -> relu+bias, add x2-upsampled branch2 (recomputed
// from partials), then 64->11 GEMM per pixel -> z (coarse logits).
// Grid: 600 blocks x 256 thr; 32 px per block; thread = (px, channel-octet).
// Block 0 also inits the bbx shard accumulators (runs before k_up_softmax).
// ---------------------------------------------------------------------------
__global__ __launch_bounds__(256) void k_combine_z(float* __restrict__ ws,
                                                   const float* __restrict__ b1,
                                                   const float* __restrict__ b2,
                                                   const float* __restrict__ w3,
                                                   const float* __restrict__ b3) {
  __shared__ float inter[64 * 32];  // [ch][px]
  __shared__ float w3s[NCl * HIDv];
  const int t = threadIdx.x;

  if (blockIdx.x == 0) {  // init bbx shards: 16*36 entries x 8 ints
    int* sh = (int*)(ws + WS_BBX);
    for (int i = t; i < NSHARD * 36 * 8; i += 256) {
      int f = i & 7;
      sh[i] = (f == 0 || f >= 5) ? 0
            : ((f == 1 || f == 3) ? 0x7fffffff : (int)0x80000000);
    }
  }
  for (int e = t; e < NCl * HIDv; e += 256) w3s[e] = w3[e];

  const int pxl = t & 31;
  const int qi = t >> 5;  // 0..7, 8 channels each
  const int gp = blockIdx.x * 32 + pxl;
  const int b = gp / PPB1, pb = gp - b * PPB1;
  const int y = pb / w1v, x = pb - y * w1v;

  // x2 bilinear (half-pixel, edge clamp)
  const float sx = x * 0.5f - 0.25f;
  const float x0f = floorf(sx);
  const float fx = sx - x0f;
  const int ix0 = iclamp((int)x0f, 0, w2v - 1);
  const int ix1 = iclamp((int)x0f + 1, 0, w2v - 1);
  const float sy = y * 0.5f - 0.25f;
  const float y0f = floorf(sy);
  const float fy = sy - y0f;
  const int iy0 = iclamp((int)y0f, 0, h2v - 1);
  const int iy1 = iclamp((int)y0f + 1, 0, h2v - 1);

  const float* p1 = ws + WS_P1;
  const float* p2 = ws + WS_P2;
  const int base2 = b * PPB2;
  const int i00 = base2 + iy0 * w2v + ix0;
  const int i01 = base2 + iy0 * w2v + ix1;
  const int i10 = base2 + iy1 * w2v + ix0;
  const int i11 = base2 + iy1 * w2v + ix1;

#pragma unroll
  for (int cc = 0; cc < 8; ++cc) {
    const int ch = qi * 8 + cc;
    float v = p1[(size_t)ch * NP1 + gp] + p1[(size_t)(HIDv + ch) * NP1 + gp] + b1[ch];
    v = fmaxf(v, 0.f);
    const float* pa = p2 + (size_t)ch * NP2;
    const float* pbp = p2 + (size_t)(HIDv + ch) * NP2;
    const float bb = b2[ch];
    float v00 = fmaxf(pa[i00] + pbp[i00] + bb, 0.f);
    float v01 = fmaxf(pa[i01] + pbp[i01] + bb, 0.f);
    float v10 = fmaxf(pa[i10] + pbp[i10] + bb, 0.f);
    float v11 = fmaxf(pa[i11] + pbp[i11] + bb, 0.f);
    float top = v00 + fx * (v01 - v00);
    float bot = v10 + fx * (v11 - v10);
    v += top + fy * (bot - top);
    inter[ch * 32 + pxl] = v;
  }
  __syncthreads();

  // z = W3 * inter + b3: out o = qi, plus o = qi+8 for qi < 3
  float* z = ws + WS_Z;
  {
    float a = b3[qi];
#pragma unroll
    for (int ch = 0; ch < 64; ++ch)
      a = fmaf(inter[ch * 32 + pxl], w3s[qi * HIDv + ch], a);
    z[((size_t)b * NCl + qi) * PPB1 + pb] = a;
  }
  if (qi < 3) {
    const int o = qi + 8;
    float a = b3[o];
#pragma unroll
    for (int ch = 0; ch < 64; ++ch)
      a = fmaf(inter[ch * 32 + pxl], w3s[o * HIDv + ch], a);
    z[((size_t)b * NCl + o) * PPB1 + pb] = a;
  }
}

// ---------------------------------------------------------------------------
// Kernel 3: x8 bilinear of z + relu + softmax + argmax + in-wave ballot bbx.
// Block = 128x2 fine tile, grid 4800; 1 px/thread (lg[11] stays in regs).
// Each wave = 64 contiguous x in one row -> ballot/popc/ctz/clz give
// count/xmin/xmax with no per-pixel atomics; 16-way-sharded global entries.
// ---------------------------------------------------------------------------
__global__ __launch_bounds__(256) void k_up_softmax(const float* __restrict__ ws,
                                                    float* __restrict__ out,
                                                    int* __restrict__ shards) {
  constexpr int ZR = 3, ZC = 18, ZN = NCl * ZR * ZC;  // 594
  __shared__ float zt[ZN];
  __shared__ int sB[4][9][4];
  const int t = threadIdx.x;
  const int tile = blockIdx.x;
  const int tx = tile % 5;
  const int ty = (tile / 5) % 240;
  const int b  = tile / 1200;
  const int base_x = tx * 16 - 1;
  const int row0 = ty * 2;
  const int base_y = (int)floorf((row0 + 0.5f) * 0.125f - 0.5f);

  // stage z tile (edge-clamped)
  const float* zb = ws + WS_Z + (size_t)b * NCl * PPB1;
  for (int e = t; e < ZN; e += 256) {
    int ch = e / (ZR * ZC);
    int rc = e % (ZR * ZC);
    int row = rc / ZC, col = rc % ZC;
    int gr = iclamp(base_y + row, 0, h1v - 1);
    int gc = iclamp(base_x + col, 0, w1v - 1);
    zt[e] = zb[(size_t)ch * PPB1 + gr * w1v + gc];
  }
  __syncthreads();

  const int x  = t & 127;
  const int rr = t >> 7;
  const int X = tx * 128 + x;
  const int Y = row0 + rr;

  const float sy = (Y + 0.5f) * 0.125f - 0.5f;
  const int y0g = (int)floorf(sy);
  const float fy = sy - (float)y0g;
  const int lry = y0g - base_y;                       // 0 or 1
  const int lcx = (2 * x + 9) >> 4;                   // 0..16
  const float fx = (float)(2 * x - 7) * 0.0625f + 1.0f - (float)lcx;

  float lg[NCl];
  float m = -1.f;
  int bi = 0;
#pragma unroll
  for (int c = 0; c < NCl; ++c) {
    const int base = c * (ZR * ZC) + lry * ZC + lcx;
    float v00 = zt[base],      v01 = zt[base + 1];
    float v10 = zt[base + ZC], v11 = zt[base + ZC + 1];
    float l0 = v00 + fy * (v10 - v00);
    float l1 = v01 + fy * (v11 - v01);
    float v = fmaxf(l0 + fx * (l1 - l0), 0.f);        // relu(logit)
    lg[c] = v;
    if (v > m) { m = v; bi = c; }                     // first-index tiebreak
  }

  float s = 0.f;
#pragma unroll
  for (int c = 0; c < NCl; ++c) {
    float e = __expf(lg[c] - m);
    lg[c] = e;
    s += e;
  }
  const float inv = __builtin_amdgcn_rcpf(s);

  const size_t r = (size_t)Y * Wf + X;
  float* prob = out + (size_t)b * NCl * PPBF;
#pragma unroll
  for (int c = 0; c < NCl; ++c)
    prob[(size_t)c * PPBF + r] = lg[c] * inv;
  out[OUT_SEG + (size_t)b * PPBF + r] = (float)bi;

  // --- bbx via wave ballot (wave = 64 contiguous x in row Y) ---
  const int lane = t & 63;
  const int wv = t >> 6;
  int cw[9], xn[9], xx[9];
#pragma unroll
  for (int c = 1; c <= 9; ++c) {
    unsigned long long msk = __ballot(bi == c);
    cw[c - 1] = (int)__popcll(msk);
    xn[c - 1] = msk ? (int)__builtin_ctzll(msk) : 0;
    xx[c - 1] = msk ? 63 - (int)__builtin_clzll(msk) : 0;
  }
  if (lane == 0) {   // lane0's X is the wave's base x
#pragma unroll
    for (int c = 0; c < 9; ++c) {
      sB[wv][c][0] = cw[c];
      sB[wv][c][1] = X + xn[c];
      sB[wv][c][2] = X + xx[c];
      sB[wv][c][3] = Y;
    }
  }
  __syncthreads();
  if (t < 9) {
    int C = 0, mn = 0x7fffffff, mx = -1, yn = 0x7fffffff, yx = -1;
#pragma unroll
    for (int w2 = 0; w2 < 4; ++w2) {
      int cc = sB[w2][t][0];
      if (cc) {
        C += cc;
        mn = min(mn, sB[w2][t][1]); mx = max(mx, sB[w2][t][2]);
        yn = min(yn, sB[w2][t][3]); yx = max(yx, sB[w2][t][3]);
      }
    }
    if (C) {
      int* e = shards + (((tile & (NSHARD - 1)) * 36) + b * 9 + t) * 8;
      atomicAdd(e + 0, C);
      atomicMin(e + 1, mn);
      atomicMax(e + 2, mx);
      atomicMin(e + 3, yn);
      atomicMax(e + 4, yx);
    }
  }
}

// ---------------------------------------------------------------------------
// Kernel 4: reduce shards, finalize bbx rows (36 x 6), THRESH = 100.
// ---------------------------------------------------------------------------
__global__ void k_bbx_final(const int* __restrict__ sh, float* __restrict__ out) {
  const int t = threadIdx.x;
  if (t >= 36) return;
  int C = 0, xn = 0x7fffffff, xx = -1, yn = 0x7fffffff, yx = -1;
  for (int s = 0; s < NSHARD; ++s) {
    const int* e = sh + (s * 36 + t) * 8;
    int c = e[0];
    if (c) {
      C += c;
      xn = min(xn, e[1]); xx = max(xx, e[2]);
      yn = min(yn, e[3]); yx = max(yx, e[4]);
    }
  }
  float* o = out + OUT_BBX + t * 6;
  if (C >= 100) {
    o[0] = (float)(t / 9);
    o[1] = (float)xn;
    o[2] = (float)yn;
    o[3] = (float)xx;
    o[4] = (float)yx;
    o[5] = (float)(t % 9 + 1);
  } else {
    for (int i = 0; i < 6; ++i) o[i] = -1.f;
  }
}

}  // namespace

extern "C" void kernel_launch(void* const* d_in, const int* in_sizes, int n_in,
                              void* d_out, int out_size, void* d_ws, size_t ws_size,
                              hipStream_t stream) {
  const float* f1 = (const float*)d_in[0];
  const float* f2 = (const float*)d_in[1];
  const float* w1 = (const float*)d_in[2];
  const float* b1 = (const float*)d_in[3];
  const float* w2 = (const float*)d_in[4];
  const float* b2 = (const float*)d_in[5];
  const float* w3 = (const float*)d_in[6];
  const float* b3 = (const float*)d_in[7];
  float* out = (float*)d_out;
  float* ws = (float*)d_ws;

  hipLaunchKernelGGL(k_gemm, dim3(750), dim3(256), 0, stream, f1, f2, w1, w2, ws);
  hipLaunchKernelGGL(k_combine_z, dim3(600), dim3(256), 0, stream, ws, b1, b2, w3, b3);
  hipLaunchKernelGGL(k_up_softmax, dim3(4800), dim3(256), 0, stream, ws, out,
                     (int*)(ws + WS_BBX));
  hipLaunchKernelGGL(k_bbx_final, dim3(1), dim3(64), 0, stream,
                     (const int*)(ws + WS_BBX), out);
}

// Round 5
// 99.433 us; speedup vs baseline: 1.1201x; 1.1201x over previous
//
#include <hip/hip_runtime.h>

#define DEVINL __device__ __forceinline__

namespace {

constexpr int NB   = 4;
constexpr int CINv = 512;
constexpr int HIDv = 64;
constexpr int NCl  = 11;   // NC+1 output channels
constexpr int h1v = 60, w1v = 80;
constexpr int h2v = 30, w2v = 40;
constexpr int Hf = 480, Wf = 640;
constexpr int PPB1 = h1v * w1v;     // 4800 coarse px / batch
constexpr int PPB2 = h2v * w2v;     // 1200
constexpr int NP1 = NB * PPB1;      // 19200
constexpr int NP2 = NB * PPB2;      // 4800
constexpr int PPBF = Hf * Wf;       // 307200 fine px / batch
constexpr int NPF = NB * PPBF;      // 1228800
constexpr int NSHARD = 16;          // bbx accumulator shards

// workspace layout (float elements). 4 K-slices of partials per conv.
constexpr size_t WS_P1  = 0;                               // 4*64*19200
constexpr size_t WS_P2  = WS_P1 + 4ull * HIDv * NP1;       // 4*64*4800
constexpr size_t WS_Z   = WS_P2 + 4ull * HIDv * NP2;       // 4*11*4800
constexpr size_t WS_BBX = WS_Z + (size_t)NB * NCl * PPB1;  // 16 shards x 36 x 8 ints

// output layout (float elements)
constexpr size_t OUT_SEG = (size_t)NB * NCl * PPBF;  // 13,516,800
constexpr size_t OUT_BBX = OUT_SEG + (size_t)NPF;    // +1,228,800

DEVINL int iclamp(int v, int lo, int hi) { return v < lo ? lo : (v > hi ? hi : v); }

// ---------------------------------------------------------------------------
// Kernel 1: 1x1 convs as wave-independent K-split GEMM.  NO LDS, NO barriers.
// One wave per block (64 thr). Wave-tile: 256 px x 16 outs x 128 K-slice.
//   A: per-lane float4 global loads (4 px/lane), register double-buffered.
//   W: uniform-address loads (og,ks from blockIdx) -> compiler scalarizes to
//      s_load / SGPRs; v_fma consumes W via the constant bus. Zero LDS traffic
//      (fp32 LDS-tiled GEMM is LDS-BW-bound at 2B/FMA vs the 0.66B/FMA
//      per-CU budget -- that was the old ~40us floor).
// Grid 1504 = conv1 75px-tiles*4og*4ks + conv2 19*4*4, XCD-swizzled so the
// 4 og-waves sharing an A-slice land on the same XCD's L2.
// ---------------------------------------------------------------------------
template <int PPB, int NPIX>
DEVINL void gemm_wave(const float* __restrict__ F, const float* __restrict__ Wm,
                      float* __restrict__ P, int pxt, int og, int ks) {
  const int lane = threadIdx.x;
  const int gp0 = pxt * 256 + lane * 4;
  const int gpc = (gp0 <= NPIX - 4) ? gp0 : (NPIX - 4);   // conv2 tail clamp
  const int b = gpc / PPB, pb = gpc - b * PPB;            // 4-px never straddles batch
  const float* aB = F + ((size_t)b * CINv + ks * 128) * PPB + pb;
  const float* wB = Wm + (size_t)og * 16 * CINv + ks * 128;

  float acc[16][4];
#pragma unroll
  for (int j = 0; j < 16; ++j)
#pragma unroll
    for (int i = 0; i < 4; ++i) acc[j][i] = 0.f;

  float4 aP[2], aQ[2];
  float wP[2][16], wQ[2][16];

  // prologue: chunk 0 (cc 0,1) -> P buffers
  aP[0] = *reinterpret_cast<const float4*>(aB);
  aP[1] = *reinterpret_cast<const float4*>(aB + (size_t)PPB);
#pragma unroll
  for (int j = 0; j < 16; ++j) {
    wP[0][j] = wB[j * CINv + 0];
    wP[1][j] = wB[j * CINv + 1];
  }

  for (int k = 0; k < 64; k += 2) {
    const int cN = 2 * (k + 1);
    // prefetch chunk k+1 -> Q
    aQ[0] = *reinterpret_cast<const float4*>(aB + (size_t)cN * PPB);
    aQ[1] = *reinterpret_cast<const float4*>(aB + (size_t)(cN + 1) * PPB);
#pragma unroll
    for (int j = 0; j < 16; ++j) {
      wQ[0][j] = wB[j * CINv + cN + 0];
      wQ[1][j] = wB[j * CINv + cN + 1];
    }
    // compute chunk k from P
#pragma unroll
    for (int c = 0; c < 2; ++c) {
      const float4 av = aP[c];
#pragma unroll
      for (int j = 0; j < 16; ++j) {
        const float wv = wP[c][j];
        acc[j][0] = fmaf(av.x, wv, acc[j][0]);
        acc[j][1] = fmaf(av.y, wv, acc[j][1]);
        acc[j][2] = fmaf(av.z, wv, acc[j][2]);
        acc[j][3] = fmaf(av.w, wv, acc[j][3]);
      }
    }
    if (k + 2 < 64) {   // prefetch chunk k+2 -> P
      const int cM = 2 * (k + 2);
      aP[0] = *reinterpret_cast<const float4*>(aB + (size_t)cM * PPB);
      aP[1] = *reinterpret_cast<const float4*>(aB + (size_t)(cM + 1) * PPB);
#pragma unroll
      for (int j = 0; j < 16; ++j) {
        wP[0][j] = wB[j * CINv + cM + 0];
        wP[1][j] = wB[j * CINv + cM + 1];
      }
    }
    // compute chunk k+1 from Q
#pragma unroll
    for (int c = 0; c < 2; ++c) {
      const float4 av = aQ[c];
#pragma unroll
      for (int j = 0; j < 16; ++j) {
        const float wv = wQ[c][j];
        acc[j][0] = fmaf(av.x, wv, acc[j][0]);
        acc[j][1] = fmaf(av.y, wv, acc[j][1]);
        acc[j][2] = fmaf(av.z, wv, acc[j][2]);
        acc[j][3] = fmaf(av.w, wv, acc[j][3]);
      }
    }
  }

  if (gp0 <= NPIX - 4) {
#pragma unroll
    for (int j = 0; j < 16; ++j) {
      float4 v;
      v.x = acc[j][0]; v.y = acc[j][1]; v.z = acc[j][2]; v.w = acc[j][3];
      *reinterpret_cast<float4*>(P + (size_t)(ks * 64 + og * 16 + j) * NPIX + gp0) = v;
    }
  }
}

__global__ __launch_bounds__(64) void k_gemm(const float* __restrict__ f1,
                                             const float* __restrict__ f2,
                                             const float* __restrict__ w1,
                                             const float* __restrict__ w2,
                                             float* __restrict__ ws) {
  // XCD swizzle: 4 og-waves of one (pxt,ks) group -> same XCD (bid%8).
  const int bid = blockIdx.x;
  const int x = bid & 7;
  const int m = bid >> 3;        // 0..187
  const int og = m & 3;
  const int g = (m >> 2) * 8 + x;  // 0..375, bijective

  if (g < 300) {
    gemm_wave<PPB1, NP1>(f1, w1, ws + WS_P1, g >> 2, og, g & 3);
  } else {
    const int g2 = g - 300;
    gemm_wave<PPB2, NP2>(f2, w2, ws + WS_P2, g2 >> 2, og, g2 & 3);
  }
}

// ---------------------------------------------------------------------------
// Kernel 2: sum 4 K-slices -> relu+bias, add x2-upsampled branch2 (slice-
// summed at the 4 taps), then 64->11 GEMM per pixel -> z (coarse logits).
// Grid: 600 blocks x 256 thr; 32 px per block; thread = (px, channel-octet).
// Block 0 also inits the bbx shard accumulators (runs before k_up_softmax).
// ---------------------------------------------------------------------------
__global__ __launch_bounds__(256) void k_combine_z(float* __restrict__ ws,
                                                   const float* __restrict__ b1,
                                                   const float* __restrict__ b2,
                                                   const float* __restrict__ w3,
                                                   const float* __restrict__ b3) {
  __shared__ float inter[64 * 32];  // [ch][px]
  __shared__ float w3s[NCl * HIDv];
  const int t = threadIdx.x;

  if (blockIdx.x == 0) {  // init bbx shards: 16*36 entries x 8 ints
    int* sh = (int*)(ws + WS_BBX);
    for (int i = t; i < NSHARD * 36 * 8; i += 256) {
      int f = i & 7;
      sh[i] = (f == 0 || f >= 5) ? 0
            : ((f == 1 || f == 3) ? 0x7fffffff : (int)0x80000000);
    }
  }
  for (int e = t; e < NCl * HIDv; e += 256) w3s[e] = w3[e];

  const int pxl = t & 31;
  const int qi = t >> 5;  // 0..7, 8 channels each
  const int gp = blockIdx.x * 32 + pxl;
  const int b = gp / PPB1, pb = gp - b * PPB1;
  const int y = pb / w1v, x = pb - y * w1v;

  // x2 bilinear (half-pixel, edge clamp)
  const float sx = x * 0.5f - 0.25f;
  const float x0f = floorf(sx);
  const float fx = sx - x0f;
  const int ix0 = iclamp((int)x0f, 0, w2v - 1);
  const int ix1 = iclamp((int)x0f + 1, 0, w2v - 1);
  const float sy = y * 0.5f - 0.25f;
  const float y0f = floorf(sy);
  const float fy = sy - y0f;
  const int iy0 = iclamp((int)y0f, 0, h2v - 1);
  const int iy1 = iclamp((int)y0f + 1, 0, h2v - 1);

  const float* p1 = ws + WS_P1;
  const float* p2 = ws + WS_P2;
  const int base2 = b * PPB2;
  const int i00 = base2 + iy0 * w2v + ix0;
  const int i01 = base2 + iy0 * w2v + ix1;
  const int i10 = base2 + iy1 * w2v + ix0;
  const int i11 = base2 + iy1 * w2v + ix1;

#pragma unroll
  for (int cc = 0; cc < 8; ++cc) {
    const int ch = qi * 8 + cc;
    float v = b1[ch];
#pragma unroll
    for (int s = 0; s < 4; ++s)
      v += p1[(size_t)(s * 64 + ch) * NP1 + gp];
    v = fmaxf(v, 0.f);
    float t00 = b2[ch], t01 = t00, t10 = t00, t11 = t00;
#pragma unroll
    for (int s = 0; s < 4; ++s) {
      const float* ps = p2 + (size_t)(s * 64 + ch) * NP2;
      t00 += ps[i00]; t01 += ps[i01]; t10 += ps[i10]; t11 += ps[i11];
    }
    const float v00 = fmaxf(t00, 0.f), v01 = fmaxf(t01, 0.f);
    const float v10 = fmaxf(t10, 0.f), v11 = fmaxf(t11, 0.f);
    const float top = v00 + fx * (v01 - v00);
    const float bot = v10 + fx * (v11 - v10);
    v += top + fy * (bot - top);
    inter[ch * 32 + pxl] = v;
  }
  __syncthreads();

  // z = W3 * inter + b3: out o = qi, plus o = qi+8 for qi < 3
  float* z = ws + WS_Z;
  {
    float a = b3[qi];
#pragma unroll
    for (int ch = 0; ch < 64; ++ch)
      a = fmaf(inter[ch * 32 + pxl], w3s[qi * HIDv + ch], a);
    z[((size_t)b * NCl + qi) * PPB1 + pb] = a;
  }
  if (qi < 3) {
    const int o = qi + 8;
    float a = b3[o];
#pragma unroll
    for (int ch = 0; ch < 64; ++ch)
      a = fmaf(inter[ch * 32 + pxl], w3s[o * HIDv + ch], a);
    z[((size_t)b * NCl + o) * PPB1 + pb] = a;
  }
}

// ---------------------------------------------------------------------------
// Kernel 3: x8 bilinear of z + relu + softmax + argmax + in-wave ballot bbx.
// Block = 128x2 fine tile, grid 4800; 1 px/thread (lg[11] stays in regs).
// ---------------------------------------------------------------------------
__global__ __launch_bounds__(256) void k_up_softmax(const float* __restrict__ ws,
                                                    float* __restrict__ out,
                                                    int* __restrict__ shards) {
  constexpr int ZR = 3, ZC = 18, ZN = NCl * ZR * ZC;  // 594
  __shared__ float zt[ZN];
  __shared__ int sB[4][9][4];
  const int t = threadIdx.x;
  const int tile = blockIdx.x;
  const int tx = tile % 5;
  const int ty = (tile / 5) % 240;
  const int b  = tile / 1200;
  const int base_x = tx * 16 - 1;
  const int row0 = ty * 2;
  const int base_y = (int)floorf((row0 + 0.5f) * 0.125f - 0.5f);

  // stage z tile (edge-clamped)
  const float* zb = ws + WS_Z + (size_t)b * NCl * PPB1;
  for (int e = t; e < ZN; e += 256) {
    int ch = e / (ZR * ZC);
    int rc = e % (ZR * ZC);
    int row = rc / ZC, col = rc % ZC;
    int gr = iclamp(base_y + row, 0, h1v - 1);
    int gc = iclamp(base_x + col, 0, w1v - 1);
    zt[e] = zb[(size_t)ch * PPB1 + gr * w1v + gc];
  }
  __syncthreads();

  const int x  = t & 127;
  const int rr = t >> 7;
  const int X = tx * 128 + x;
  const int Y = row0 + rr;

  const float sy = (Y + 0.5f) * 0.125f - 0.5f;
  const int y0g = (int)floorf(sy);
  const float fy = sy - (float)y0g;
  const int lry = y0g - base_y;                       // 0 or 1
  const int lcx = (2 * x + 9) >> 4;                   // 0..16
  const float fx = (float)(2 * x - 7) * 0.0625f + 1.0f - (float)lcx;

  float lg[NCl];
  float m = -1.f;
  int bi = 0;
#pragma unroll
  for (int c = 0; c < NCl; ++c) {
    const int base = c * (ZR * ZC) + lry * ZC + lcx;
    float v00 = zt[base],      v01 = zt[base + 1];
    float v10 = zt[base + ZC], v11 = zt[base + ZC + 1];
    float l0 = v00 + fy * (v10 - v00);
    float l1 = v01 + fy * (v11 - v01);
    float v = fmaxf(l0 + fx * (l1 - l0), 0.f);        // relu(logit)
    lg[c] = v;
    if (v > m) { m = v; bi = c; }                     // first-index tiebreak
  }

  float s = 0.f;
#pragma unroll
  for (int c = 0; c < NCl; ++c) {
    float e = __expf(lg[c] - m);
    lg[c] = e;
    s += e;
  }
  const float inv = __builtin_amdgcn_rcpf(s);

  const size_t r = (size_t)Y * Wf + X;
  float* prob = out + (size_t)b * NCl * PPBF;
#pragma unroll
  for (int c = 0; c < NCl; ++c)
    prob[(size_t)c * PPBF + r] = lg[c] * inv;
  out[OUT_SEG + (size_t)b * PPBF + r] = (float)bi;

  // --- bbx via wave ballot (wave = 64 contiguous x in row Y) ---
  const int lane = t & 63;
  const int wv = t >> 6;
  int cw[9], xn[9], xx[9];
#pragma unroll
  for (int c = 1; c <= 9; ++c) {
    unsigned long long msk = __ballot(bi == c);
    cw[c - 1] = (int)__popcll(msk);
    xn[c - 1] = msk ? (int)__builtin_ctzll(msk) : 0;
    xx[c - 1] = msk ? 63 - (int)__builtin_clzll(msk) : 0;
  }
  if (lane == 0) {   // lane0's X is the wave's base x
#pragma unroll
    for (int c = 0; c < 9; ++c) {
      sB[wv][c][0] = cw[c];
      sB[wv][c][1] = X + xn[c];
      sB[wv][c][2] = X + xx[c];
      sB[wv][c][3] = Y;
    }
  }
  __syncthreads();
  if (t < 9) {
    int C = 0, mn = 0x7fffffff, mx = -1, yn = 0x7fffffff, yx = -1;
#pragma unroll
    for (int w2 = 0; w2 < 4; ++w2) {
      int cc = sB[w2][t][0];
      if (cc) {
        C += cc;
        mn = min(mn, sB[w2][t][1]); mx = max(mx, sB[w2][t][2]);
        yn = min(yn, sB[w2][t][3]); yx = max(yx, sB[w2][t][3]);
      }
    }
    if (C) {
      int* e = shards + (((tile & (NSHARD - 1)) * 36) + b * 9 + t) * 8;
      atomicAdd(e + 0, C);
      atomicMin(e + 1, mn);
      atomicMax(e + 2, mx);
      atomicMin(e + 3, yn);
      atomicMax(e + 4, yx);
    }
  }
}

// ---------------------------------------------------------------------------
// Kernel 4: reduce shards, finalize bbx rows (36 x 6), THRESH = 100.
// ---------------------------------------------------------------------------
__global__ void k_bbx_final(const int* __restrict__ sh, float* __restrict__ out) {
  const int t = threadIdx.x;
  if (t >= 36) return;
  int C = 0, xn = 0x7fffffff, xx = -1, yn = 0x7fffffff, yx = -1;
  for (int s = 0; s < NSHARD; ++s) {
    const int* e = sh + (s * 36 + t) * 8;
    int c = e[0];
    if (c) {
      C += c;
      xn = min(xn, e[1]); xx = max(xx, e[2]);
      yn = min(yn, e[3]); yx = max(yx, e[4]);
    }
  }
  float* o = out + OUT_BBX + t * 6;
  if (C >= 100) {
    o[0] = (float)(t / 9);
    o[1] = (float)xn;
    o[2] = (float)yn;
    o[3] = (float)xx;
    o[4] = (float)yx;
    o[5] = (float)(t % 9 + 1);
  } else {
    for (int i = 0; i < 6; ++i) o[i] = -1.f;
  }
}

}  // namespace

extern "C" void kernel_launch(void* const* d_in, const int* in_sizes, int n_in,
                              void* d_out, int out_size, void* d_ws, size_t ws_size,
                              hipStream_t stream) {
  const float* f1 = (const float*)d_in[0];
  const float* f2 = (const float*)d_in[1];
  const float* w1 = (const float*)d_in[2];
  const float* b1 = (const float*)d_in[3];
  const float* w2 = (const float*)d_in[4];
  const float* b2 = (const float*)d_in[5];
  const float* w3 = (const float*)d_in[6];
  const float* b3 = (const float*)d_in[7];
  float* out = (float*)d_out;
  float* ws = (float*)d_ws;

  hipLaunchKernelGGL(k_gemm, dim3(1504), dim3(64), 0, stream, f1, f2, w1, w2, ws);
  hipLaunchKernelGGL(k_combine_z, dim3(600), dim3(256), 0, stream, ws, b1, b2, w3, b3);
  hipLaunchKernelGGL(k_up_softmax, dim3(4800), dim3(256), 0, stream, ws, out,
                     (int*)(ws + WS_BBX));
  hipLaunchKernelGGL(k_bbx_final, dim3(1), dim3(64), 0, stream,
                     (const int*)(ws + WS_BBX), out);
}

// Round 6
// 78.178 us; speedup vs baseline: 1.4247x; 1.2719x over previous
//
#include <hip/hip_runtime.h>

#define DEVINL __device__ __forceinline__

namespace {

constexpr int NB   = 4;
constexpr int CINv = 512;
constexpr int HIDv = 64;
constexpr int NCl  = 11;   // NC+1 output channels
constexpr int h1v = 60, w1v = 80;
constexpr int h2v = 30, w2v = 40;
constexpr int Hf = 480, Wf = 640;
constexpr int PPB1 = h1v * w1v;     // 4800 coarse px / batch
constexpr int PPB2 = h2v * w2v;     // 1200
constexpr int NP1 = NB * PPB1;      // 19200
constexpr int NP2 = NB * PPB2;      // 4800
constexpr int PPBF = Hf * Wf;       // 307200 fine px / batch
constexpr int NPF = NB * PPBF;      // 1228800
constexpr int NSHARD = 16;          // bbx accumulator shards

// workspace layout (float elements). 4 K-slices of partials per conv.
constexpr size_t WS_P1  = 0;                               // 4*64*19200
constexpr size_t WS_P2  = WS_P1 + 4ull * HIDv * NP1;       // 4*64*4800
constexpr size_t WS_Z   = WS_P2 + 4ull * HIDv * NP2;       // 4*11*4800
constexpr size_t WS_BBX = WS_Z + (size_t)NB * NCl * PPB1;  // 16 shards x 36 x 8 ints

// output layout (float elements)
constexpr size_t OUT_SEG = (size_t)NB * NCl * PPBF;  // 13,516,800
constexpr size_t OUT_BBX = OUT_SEG + (size_t)NPF;    // +1,228,800

DEVINL int iclamp(int v, int lo, int hi) { return v < lo ? lo : (v > hi ? hi : v); }

// ---------------------------------------------------------------------------
// Kernel 1: 1x1 convs as wave-independent K-split GEMM.  NO LDS, NO barriers.
// One wave per block (64 thr). Wave-tile: 256 px x 8 outs x 128 K-slice
// (v2: 8 outs, was 16 -> 3008 waves = 2.9/SIMD; round-5's 1504 waves =
// 1.47/SIMD was issue/latency-starved at VALUBusy 26%).
//   A: per-lane float4 global loads (4 px/lane), register double-buffered.
//   W: uniform-address loads -> compiler scalarizes to s_load / SGPRs.
// Family swizzle: bid = og*376 + f  (376 % 8 == 0), so all 8 og-waves of an
// A-slice family f share bid%8 -> same XCD -> A reuse served by one L2.
// ---------------------------------------------------------------------------
template <int PPB, int NPIX>
DEVINL void gemm_wave(const float* __restrict__ F, const float* __restrict__ Wm,
                      float* __restrict__ P, int pxt, int og, int ks) {
  const int lane = threadIdx.x;
  const int gp0 = pxt * 256 + lane * 4;
  const int gpc = (gp0 <= NPIX - 4) ? gp0 : (NPIX - 4);   // conv2 tail clamp
  const int b = gpc / PPB, pb = gpc - b * PPB;            // 4-px never straddles batch
  const float* aB = F + ((size_t)b * CINv + ks * 128) * PPB + pb;
  const float* wB = Wm + (size_t)og * 8 * CINv + ks * 128;

  float acc[8][4];
#pragma unroll
  for (int j = 0; j < 8; ++j)
#pragma unroll
    for (int i = 0; i < 4; ++i) acc[j][i] = 0.f;

  float4 aP[2], aQ[2];
  float wP[2][8], wQ[2][8];

  // prologue: chunk 0 (cc 0,1) -> P buffers
  aP[0] = *reinterpret_cast<const float4*>(aB);
  aP[1] = *reinterpret_cast<const float4*>(aB + (size_t)PPB);
#pragma unroll
  for (int j = 0; j < 8; ++j) {
    wP[0][j] = wB[j * CINv + 0];
    wP[1][j] = wB[j * CINv + 1];
  }

  for (int k = 0; k < 64; k += 2) {
    const int cN = 2 * (k + 1);
    // prefetch chunk k+1 -> Q
    aQ[0] = *reinterpret_cast<const float4*>(aB + (size_t)cN * PPB);
    aQ[1] = *reinterpret_cast<const float4*>(aB + (size_t)(cN + 1) * PPB);
#pragma unroll
    for (int j = 0; j < 8; ++j) {
      wQ[0][j] = wB[j * CINv + cN + 0];
      wQ[1][j] = wB[j * CINv + cN + 1];
    }
    // compute chunk k from P
#pragma unroll
    for (int c = 0; c < 2; ++c) {
      const float4 av = aP[c];
#pragma unroll
      for (int j = 0; j < 8; ++j) {
        const float wv = wP[c][j];
        acc[j][0] = fmaf(av.x, wv, acc[j][0]);
        acc[j][1] = fmaf(av.y, wv, acc[j][1]);
        acc[j][2] = fmaf(av.z, wv, acc[j][2]);
        acc[j][3] = fmaf(av.w, wv, acc[j][3]);
      }
    }
    if (k + 2 < 64) {   // prefetch chunk k+2 -> P
      const int cM = 2 * (k + 2);
      aP[0] = *reinterpret_cast<const float4*>(aB + (size_t)cM * PPB);
      aP[1] = *reinterpret_cast<const float4*>(aB + (size_t)(cM + 1) * PPB);
#pragma unroll
      for (int j = 0; j < 8; ++j) {
        wP[0][j] = wB[j * CINv + cM + 0];
        wP[1][j] = wB[j * CINv + cM + 1];
      }
    }
    // compute chunk k+1 from Q
#pragma unroll
    for (int c = 0; c < 2; ++c) {
      const float4 av = aQ[c];
#pragma unroll
      for (int j = 0; j < 8; ++j) {
        const float wv = wQ[c][j];
        acc[j][0] = fmaf(av.x, wv, acc[j][0]);
        acc[j][1] = fmaf(av.y, wv, acc[j][1]);
        acc[j][2] = fmaf(av.z, wv, acc[j][2]);
        acc[j][3] = fmaf(av.w, wv, acc[j][3]);
      }
    }
  }

  if (gp0 <= NPIX - 4) {
#pragma unroll
    for (int j = 0; j < 8; ++j) {
      float4 v;
      v.x = acc[j][0]; v.y = acc[j][1]; v.z = acc[j][2]; v.w = acc[j][3];
      *reinterpret_cast<float4*>(P + (size_t)(ks * 64 + og * 8 + j) * NPIX + gp0) = v;
    }
  }
}

__global__ __launch_bounds__(64) void k_gemm(const float* __restrict__ f1,
                                             const float* __restrict__ f2,
                                             const float* __restrict__ w1,
                                             const float* __restrict__ w2,
                                             float* __restrict__ ws) {
  // bid = og*376 + f ; f = family (pxt,ks): conv1 f<300, conv2 f-300.
  const int bid = blockIdx.x;
  const int og = bid / 376;        // 0..7
  const int f  = bid - og * 376;   // 0..375

  if (f < 300) {
    gemm_wave<PPB1, NP1>(f1, w1, ws + WS_P1, f >> 2, og, f & 3);
  } else {
    const int f2i = f - 300;
    gemm_wave<PPB2, NP2>(f2, w2, ws + WS_P2, f2i >> 2, og, f2i & 3);
  }
}

// ---------------------------------------------------------------------------
// Kernel 2: sum 4 K-slices -> relu+bias, add x2-upsampled branch2 (slice-
// summed at the 4 taps), then 64->11 GEMM per pixel -> z (coarse logits).
// Grid: 600 blocks x 256 thr; 32 px per block; thread = (px, channel-octet).
// Block 0 also inits the bbx shard accumulators (runs before k_up_softmax).
// ---------------------------------------------------------------------------
__global__ __launch_bounds__(256) void k_combine_z(float* __restrict__ ws,
                                                   const float* __restrict__ b1,
                                                   const float* __restrict__ b2,
                                                   const float* __restrict__ w3,
                                                   const float* __restrict__ b3) {
  __shared__ float inter[64 * 32];  // [ch][px]
  __shared__ float w3s[NCl * HIDv];
  const int t = threadIdx.x;

  if (blockIdx.x == 0) {  // init bbx shards: 16*36 entries x 8 ints
    int* sh = (int*)(ws + WS_BBX);
    for (int i = t; i < NSHARD * 36 * 8; i += 256) {
      int f = i & 7;
      sh[i] = (f == 0 || f >= 5) ? 0
            : ((f == 1 || f == 3) ? 0x7fffffff : (int)0x80000000);
    }
  }
  for (int e = t; e < NCl * HIDv; e += 256) w3s[e] = w3[e];

  const int pxl = t & 31;
  const int qi = t >> 5;  // 0..7, 8 channels each
  const int gp = blockIdx.x * 32 + pxl;
  const int b = gp / PPB1, pb = gp - b * PPB1;
  const int y = pb / w1v, x = pb - y * w1v;

  // x2 bilinear (half-pixel, edge clamp)
  const float sx = x * 0.5f - 0.25f;
  const float x0f = floorf(sx);
  const float fx = sx - x0f;
  const int ix0 = iclamp((int)x0f, 0, w2v - 1);
  const int ix1 = iclamp((int)x0f + 1, 0, w2v - 1);
  const float sy = y * 0.5f - 0.25f;
  const float y0f = floorf(sy);
  const float fy = sy - y0f;
  const int iy0 = iclamp((int)y0f, 0, h2v - 1);
  const int iy1 = iclamp((int)y0f + 1, 0, h2v - 1);

  const float* p1 = ws + WS_P1;
  const float* p2 = ws + WS_P2;
  const int base2 = b * PPB2;
  const int i00 = base2 + iy0 * w2v + ix0;
  const int i01 = base2 + iy0 * w2v + ix1;
  const int i10 = base2 + iy1 * w2v + ix0;
  const int i11 = base2 + iy1 * w2v + ix1;

#pragma unroll
  for (int cc = 0; cc < 8; ++cc) {
    const int ch = qi * 8 + cc;
    float v = b1[ch];
#pragma unroll
    for (int s = 0; s < 4; ++s)
      v += p1[(size_t)(s * 64 + ch) * NP1 + gp];
    v = fmaxf(v, 0.f);
    float t00 = b2[ch], t01 = t00, t10 = t00, t11 = t00;
#pragma unroll
    for (int s = 0; s < 4; ++s) {
      const float* ps = p2 + (size_t)(s * 64 + ch) * NP2;
      t00 += ps[i00]; t01 += ps[i01]; t10 += ps[i10]; t11 += ps[i11];
    }
    const float v00 = fmaxf(t00, 0.f), v01 = fmaxf(t01, 0.f);
    const float v10 = fmaxf(t10, 0.f), v11 = fmaxf(t11, 0.f);
    const float top = v00 + fx * (v01 - v00);
    const float bot = v10 + fx * (v11 - v10);
    v += top + fy * (bot - top);
    inter[ch * 32 + pxl] = v;
  }
  __syncthreads();

  // z = W3 * inter + b3: out o = qi, plus o = qi+8 for qi < 3
  float* z = ws + WS_Z;
  {
    float a = b3[qi];
#pragma unroll
    for (int ch = 0; ch < 64; ++ch)
      a = fmaf(inter[ch * 32 + pxl], w3s[qi * HIDv + ch], a);
    z[((size_t)b * NCl + qi) * PPB1 + pb] = a;
  }
  if (qi < 3) {
    const int o = qi + 8;
    float a = b3[o];
#pragma unroll
    for (int ch = 0; ch < 64; ++ch)
      a = fmaf(inter[ch * 32 + pxl], w3s[o * HIDv + ch], a);
    z[((size_t)b * NCl + o) * PPB1 + pb] = a;
  }
}

// ---------------------------------------------------------------------------
// Kernel 3: x8 bilinear of z + relu + softmax + argmax + in-wave ballot bbx.
// Block = 128x2 fine tile, grid 4800; 1 px/thread (lg[11] stays in regs).
// ---------------------------------------------------------------------------
__global__ __launch_bounds__(256) void k_up_softmax(const float* __restrict__ ws,
                                                    float* __restrict__ out,
                                                    int* __restrict__ shards) {
  constexpr int ZR = 3, ZC = 18, ZN = NCl * ZR * ZC;  // 594
  __shared__ float zt[ZN];
  __shared__ int sB[4][9][4];
  const int t = threadIdx.x;
  const int tile = blockIdx.x;
  const int tx = tile % 5;
  const int ty = (tile / 5) % 240;
  const int b  = tile / 1200;
  const int base_x = tx * 16 - 1;
  const int row0 = ty * 2;
  const int base_y = (int)floorf((row0 + 0.5f) * 0.125f - 0.5f);

  // stage z tile (edge-clamped)
  const float* zb = ws + WS_Z + (size_t)b * NCl * PPB1;
  for (int e = t; e < ZN; e += 256) {
    int ch = e / (ZR * ZC);
    int rc = e % (ZR * ZC);
    int row = rc / ZC, col = rc % ZC;
    int gr = iclamp(base_y + row, 0, h1v - 1);
    int gc = iclamp(base_x + col, 0, w1v - 1);
    zt[e] = zb[(size_t)ch * PPB1 + gr * w1v + gc];
  }
  __syncthreads();

  const int x  = t & 127;
  const int rr = t >> 7;
  const int X = tx * 128 + x;
  const int Y = row0 + rr;

  const float sy = (Y + 0.5f) * 0.125f - 0.5f;
  const int y0g = (int)floorf(sy);
  const float fy = sy - (float)y0g;
  const int lry = y0g - base_y;                       // 0 or 1
  const int lcx = (2 * x + 9) >> 4;                   // 0..16
  const float fx = (float)(2 * x - 7) * 0.0625f + 1.0f - (float)lcx;

  float lg[NCl];
  float m = -1.f;
  int bi = 0;
#pragma unroll
  for (int c = 0; c < NCl; ++c) {
    const int base = c * (ZR * ZC) + lry * ZC + lcx;
    float v00 = zt[base],      v01 = zt[base + 1];
    float v10 = zt[base + ZC], v11 = zt[base + ZC + 1];
    float l0 = v00 + fy * (v10 - v00);
    float l1 = v01 + fy * (v11 - v01);
    float v = fmaxf(l0 + fx * (l1 - l0), 0.f);        // relu(logit)
    lg[c] = v;
    if (v > m) { m = v; bi = c; }                     // first-index tiebreak
  }

  float s = 0.f;
#pragma unroll
  for (int c = 0; c < NCl; ++c) {
    float e = __expf(lg[c] - m);
    lg[c] = e;
    s += e;
  }
  const float inv = __builtin_amdgcn_rcpf(s);

  const size_t r = (size_t)Y * Wf + X;
  float* prob = out + (size_t)b * NCl * PPBF;
#pragma unroll
  for (int c = 0; c < NCl; ++c)
    prob[(size_t)c * PPBF + r] = lg[c] * inv;
  out[OUT_SEG + (size_t)b * PPBF + r] = (float)bi;

  // --- bbx via wave ballot (wave = 64 contiguous x in row Y) ---
  const int lane = t & 63;
  const int wv = t >> 6;
  int cw[9], xn[9], xx[9];
#pragma unroll
  for (int c = 1; c <= 9; ++c) {
    unsigned long long msk = __ballot(bi == c);
    cw[c - 1] = (int)__popcll(msk);
    xn[c - 1] = msk ? (int)__builtin_ctzll(msk) : 0;
    xx[c - 1] = msk ? 63 - (int)__builtin_clzll(msk) : 0;
  }
  if (lane == 0) {   // lane0's X is the wave's base x
#pragma unroll
    for (int c = 0; c < 9; ++c) {
      sB[wv][c][0] = cw[c];
      sB[wv][c][1] = X + xn[c];
      sB[wv][c][2] = X + xx[c];
      sB[wv][c][3] = Y;
    }
  }
  __syncthreads();
  if (t < 9) {
    int C = 0, mn = 0x7fffffff, mx = -1, yn = 0x7fffffff, yx = -1;
#pragma unroll
    for (int w2 = 0; w2 < 4; ++w2) {
      int cc = sB[w2][t][0];
      if (cc) {
        C += cc;
        mn = min(mn, sB[w2][t][1]); mx = max(mx, sB[w2][t][2]);
        yn = min(yn, sB[w2][t][3]); yx = max(yx, sB[w2][t][3]);
      }
    }
    if (C) {
      int* e = shards + (((tile & (NSHARD - 1)) * 36) + b * 9 + t) * 8;
      atomicAdd(e + 0, C);
      atomicMin(e + 1, mn);
      atomicMax(e + 2, mx);
      atomicMin(e + 3, yn);
      atomicMax(e + 4, yx);
    }
  }
}

// ---------------------------------------------------------------------------
// Kernel 4: reduce shards, finalize bbx rows (36 x 6), THRESH = 100.
// ---------------------------------------------------------------------------
__global__ void k_bbx_final(const int* __restrict__ sh, float* __restrict__ out) {
  const int t = threadIdx.x;
  if (t >= 36) return;
  int C = 0, xn = 0x7fffffff, xx = -1, yn = 0x7fffffff, yx = -1;
  for (int s = 0; s < NSHARD; ++s) {
    const int* e = sh + (s * 36 + t) * 8;
    int c = e[0];
    if (c) {
      C += c;
      xn = min(xn, e[1]); xx = max(xx, e[2]);
      yn = min(yn, e[3]); yx = max(yx, e[4]);
    }
  }
  float* o = out + OUT_BBX + t * 6;
  if (C >= 100) {
    o[0] = (float)(t / 9);
    o[1] = (float)xn;
    o[2] = (float)yn;
    o[3] = (float)xx;
    o[4] = (float)yx;
    o[5] = (float)(t % 9 + 1);
  } else {
    for (int i = 0; i < 6; ++i) o[i] = -1.f;
  }
}

}  // namespace

extern "C" void kernel_launch(void* const* d_in, const int* in_sizes, int n_in,
                              void* d_out, int out_size, void* d_ws, size_t ws_size,
                              hipStream_t stream) {
  const float* f1 = (const float*)d_in[0];
  const float* f2 = (const float*)d_in[1];
  const float* w1 = (const float*)d_in[2];
  const float* b1 = (const float*)d_in[3];
  const float* w2 = (const float*)d_in[4];
  const float* b2 = (const float*)d_in[5];
  const float* w3 = (const float*)d_in[6];
  const float* b3 = (const float*)d_in[7];
  float* out = (float*)d_out;
  float* ws = (float*)d_ws;

  hipLaunchKernelGGL(k_gemm, dim3(3008), dim3(64), 0, stream, f1, f2, w1, w2, ws);
  hipLaunchKernelGGL(k_combine_z, dim3(600), dim3(256), 0, stream, ws, b1, b2, w3, b3);
  hipLaunchKernelGGL(k_up_softmax, dim3(4800), dim3(256), 0, stream, ws, out,
                     (int*)(ws + WS_BBX));
  hipLaunchKernelGGL(k_bbx_final, dim3(1), dim3(64), 0, stream,
                     (const int*)(ws + WS_BBX), out);
}